// Round 1
// baseline (856.469 us; speedup 1.0000x reference)
//
#include <hip/hip_runtime.h>
#include <hip/hip_bf16.h>

// GAT (3 layers) + MLP head for CiteSeer-like synthetic graph.
// N=50000 nodes, E=800000 edges (+N self loops), D_IN=D=128, H=256, C=6.
//
// Pipeline per launch (all on `stream`, graph-capture safe):
//   1. CSR build: deg histogram -> exclusive scan -> scatter (src grouped by dst)
//   2. 3x GAT layer: h = x@W (fp32 tiled GEMM); alpha_src/dst per node (wave dot);
//      per-node 2-pass segment softmax + weighted aggregate (wave per node)
//   3. MLP: relu(h@Wm1+bm1) (GEMM), then wave-per-node 256->6 projection.

#define TM 64
#define TN 64
#define TK 32

__global__ __launch_bounds__(256) void k_hist(const int* __restrict__ ei, int* __restrict__ deg,
                                              int E_, int N_) {
    int e = blockIdx.x * 256 + threadIdx.x;
    int total = E_ + N_;
    if (e >= total) return;
    int d = (e < E_) ? ei[E_ + e] : (e - E_);
    atomicAdd(&deg[d], 1);
}

__global__ __launch_bounds__(1024) void k_scan(const int* __restrict__ deg, int* __restrict__ off, int n) {
    __shared__ int wsum[16];
    __shared__ int wpre[16];
    int tid = threadIdx.x, lane = tid & 63, wid = tid >> 6;
    int carry = 0;
    for (int base = 0; base < n; base += 1024) {
        int i = base + tid;
        int orig = (i < n) ? deg[i] : 0;
        int v = orig;
        #pragma unroll
        for (int d = 1; d < 64; d <<= 1) {
            int t = __shfl_up(v, d);
            if (lane >= d) v += t;
        }
        if (lane == 63) wsum[wid] = v;
        __syncthreads();
        if (wid == 0) {
            int s = (lane < 16) ? wsum[lane] : 0;
            #pragma unroll
            for (int d = 1; d < 16; d <<= 1) {
                int t = __shfl_up(s, d);
                if (lane >= d) s += t;
            }
            if (lane < 16) wpre[lane] = s;
        }
        __syncthreads();
        int woff = (wid > 0) ? wpre[wid - 1] : 0;
        if (i < n) off[i] = carry + woff + (v - orig);
        carry += wpre[15];
        __syncthreads();
    }
    if (tid == 0) off[n] = carry;
}

__global__ __launch_bounds__(256) void k_scatter(const int* __restrict__ ei, const int* __restrict__ off,
                                                 int* __restrict__ cur, int* __restrict__ csrc,
                                                 int E_, int N_) {
    int e = blockIdx.x * 256 + threadIdx.x;
    int total = E_ + N_;
    if (e >= total) return;
    int s, d;
    if (e < E_) { s = ei[e]; d = ei[E_ + e]; }
    else        { s = e - E_; d = e - E_; }
    int pos = off[d] + atomicAdd(&cur[d], 1);
    csrc[pos] = s;
}

// C[M x Ncol] = A[M x K] @ B[K x Ncol] (+bias)(relu). 64x64 tile, 256 thr, 4x4/thread.
__global__ __launch_bounds__(256) void k_gemm(const float* __restrict__ A, const float* __restrict__ B,
                                              const float* __restrict__ bias, float* __restrict__ C,
                                              int M, int Ncol, int K, int has_bias, int relu) {
    __shared__ float As[TK][TM + 1];
    __shared__ float Bs[TK][TN + 1];
    int bm = blockIdx.y * TM;
    int bn = blockIdx.x * TN;
    int tid = threadIdx.x;
    int tr = (tid / 16) * 4;
    int tc = (tid % 16) * 4;
    float acc[4][4] = {};
    for (int k0 = 0; k0 < K; k0 += TK) {
        for (int t = tid; t < TM * TK; t += 256) {
            int i = t / TK, j = t % TK;
            int row = bm + i;
            As[j][i] = (row < M) ? A[(size_t)row * K + k0 + j] : 0.f;
        }
        for (int t = tid; t < TK * TN; t += 256) {
            int i = t / TN, j = t % TN;
            Bs[i][j] = B[(size_t)(k0 + i) * Ncol + bn + j];
        }
        __syncthreads();
        #pragma unroll
        for (int kk = 0; kk < TK; ++kk) {
            float a[4], b[4];
            #pragma unroll
            for (int x = 0; x < 4; ++x) a[x] = As[kk][tr + x];
            #pragma unroll
            for (int y = 0; y < 4; ++y) b[y] = Bs[kk][tc + y];
            #pragma unroll
            for (int x = 0; x < 4; ++x)
                #pragma unroll
                for (int y = 0; y < 4; ++y)
                    acc[x][y] += a[x] * b[y];
        }
        __syncthreads();
    }
    #pragma unroll
    for (int x = 0; x < 4; ++x) {
        int row = bm + tr + x;
        if (row >= M) continue;
        #pragma unroll
        for (int y = 0; y < 4; ++y) {
            int col = bn + tc + y;
            float v = acc[x][y];
            if (has_bias) v += bias[col];
            if (relu) v = fmaxf(v, 0.f);
            C[(size_t)row * Ncol + col] = v;
        }
    }
}

// per-node attention coefficients: avs[n] = h[n].asrc, avd[n] = h[n].adst  (D=128)
__global__ __launch_bounds__(256) void k_alpha(const float* __restrict__ h, const float* __restrict__ asrc,
                                               const float* __restrict__ adst, float* __restrict__ avs,
                                               float* __restrict__ avd, int n) {
    int w = (blockIdx.x * 256 + threadIdx.x) >> 6;
    int lane = threadIdx.x & 63;
    if (w >= n) return;
    float h0 = h[(size_t)w * 128 + lane];
    float h1 = h[(size_t)w * 128 + 64 + lane];
    float vs = h0 * asrc[lane] + h1 * asrc[64 + lane];
    float vd = h0 * adst[lane] + h1 * adst[64 + lane];
    #pragma unroll
    for (int d = 32; d > 0; d >>= 1) {
        vs += __shfl_down(vs, d);
        vd += __shfl_down(vd, d);
    }
    if (lane == 0) { avs[w] = vs; avd[w] = vd; }
}

// one wave per dst node: segment softmax (2-pass) + weighted feature aggregate + bias + relu
__global__ __launch_bounds__(256) void k_aggregate(const float* __restrict__ h, const int* __restrict__ off,
                                                   const int* __restrict__ csrc, const float* __restrict__ avs,
                                                   const float* __restrict__ avd, const float* __restrict__ bias,
                                                   float* __restrict__ out, int n) {
    int w = (blockIdx.x * 256 + threadIdx.x) >> 6;
    int lane = threadIdx.x & 63;
    if (w >= n) return;
    int beg = off[w], end = off[w + 1];
    float adn = avd[w];
    // pass 1: max score (edge-parallel across lanes)
    float m = -1e30f;
    for (int j = beg + lane; j < end; j += 64) {
        int s = csrc[j];
        float sc = avs[s] + adn;
        sc = (sc < 0.f) ? 0.2f * sc : sc;
        m = fmaxf(m, sc);
    }
    #pragma unroll
    for (int d = 32; d > 0; d >>= 1) m = fmaxf(m, __shfl_down(m, d));
    m = __shfl(m, 0);
    // pass 2: wave-uniform loop over edges; accumulate e and e*h[src]
    float acc0 = 0.f, acc1 = 0.f, ssum = 0.f;
    for (int j = beg; j < end; ++j) {
        int s = csrc[j];
        float sc = avs[s] + adn;
        sc = (sc < 0.f) ? 0.2f * sc : sc;
        float e = __expf(sc - m);
        ssum += e;
        acc0 += e * h[(size_t)s * 128 + lane];
        acc1 += e * h[(size_t)s * 128 + 64 + lane];
    }
    float inv = 1.f / ssum;
    out[(size_t)w * 128 + lane]      = fmaxf(acc0 * inv + bias[lane], 0.f);
    out[(size_t)w * 128 + 64 + lane] = fmaxf(acc1 * inv + bias[64 + lane], 0.f);
}

// out[n,c] = mid[n,:256] @ Wm2[:,c] + bm2[c]; one wave per node, Wm2 in LDS
__global__ __launch_bounds__(256) void k_mlp2(const float* __restrict__ mid, const float* __restrict__ W2,
                                              const float* __restrict__ b2, float* __restrict__ out, int n) {
    __shared__ float Ws[256 * 6];
    int tid = threadIdx.x;
    for (int t = tid; t < 256 * 6; t += 256) Ws[t] = W2[t];
    __syncthreads();
    int w = (blockIdx.x * 256 + tid) >> 6;
    int lane = tid & 63;
    if (w >= n) return;
    float acc[6] = {0.f, 0.f, 0.f, 0.f, 0.f, 0.f};
    const float* mrow = mid + (size_t)w * 256;
    for (int k = lane; k < 256; k += 64) {
        float mv = mrow[k];
        #pragma unroll
        for (int c = 0; c < 6; ++c) acc[c] += mv * Ws[k * 6 + c];
    }
    #pragma unroll
    for (int c = 0; c < 6; ++c)
        #pragma unroll
        for (int d = 32; d > 0; d >>= 1) acc[c] += __shfl_down(acc[c], d);
    if (lane == 0) {
        #pragma unroll
        for (int c = 0; c < 6; ++c) out[(size_t)w * 6 + c] = acc[c] + b2[c];
    }
}

extern "C" void kernel_launch(void* const* d_in, const int* in_sizes, int n_in,
                              void* d_out, int out_size, void* d_ws, size_t ws_size,
                              hipStream_t stream) {
    const float* x   = (const float*)d_in[0];
    const int*   ei  = (const int*)d_in[1];
    const float* W[3]    = {(const float*)d_in[2], (const float*)d_in[6], (const float*)d_in[10]};
    const float* bL[3]   = {(const float*)d_in[3], (const float*)d_in[7], (const float*)d_in[11]};
    const float* asr[3]  = {(const float*)d_in[4], (const float*)d_in[8], (const float*)d_in[12]};
    const float* ads[3]  = {(const float*)d_in[5], (const float*)d_in[9], (const float*)d_in[13]};
    const float* Wm1 = (const float*)d_in[14];
    const float* bm1 = (const float*)d_in[15];
    const float* Wm2 = (const float*)d_in[16];
    const float* bm2 = (const float*)d_in[17];
    float* out = (float*)d_out;

    const int N_ = in_sizes[0] / 128;
    const int E_ = in_sizes[1] / 2;
    const int TOT = E_ + N_;

    // workspace carve-up (256B aligned)
    char* p = (char*)d_ws;
    auto alloc = [&](size_t bytes) { void* r = (void*)p; p += (bytes + 255) & ~(size_t)255; return r; };
    int*   deg  = (int*)alloc((size_t)N_ * 4);
    int*   cur  = (int*)alloc((size_t)N_ * 4);
    int*   off  = (int*)alloc((size_t)(N_ + 1) * 4);
    int*   csrc = (int*)alloc((size_t)TOT * 4);
    float* avs  = (float*)alloc((size_t)N_ * 4);
    float* avd  = (float*)alloc((size_t)N_ * 4);
    float* buf1 = (float*)alloc((size_t)N_ * 256 * 4);  // h-transform (128 cols) / mlp mid (256 cols)
    float* buf2 = (float*)alloc((size_t)N_ * 128 * 4);  // aggregated layer output

    // ---- CSR build ----
    hipMemsetAsync(deg, 0, (size_t)N_ * 4, stream);
    k_hist<<<(TOT + 255) / 256, 256, 0, stream>>>(ei, deg, E_, N_);
    k_scan<<<1, 1024, 0, stream>>>(deg, off, N_);
    hipMemsetAsync(cur, 0, (size_t)N_ * 4, stream);
    k_scatter<<<(TOT + 255) / 256, 256, 0, stream>>>(ei, off, cur, csrc, E_, N_);

    const int wave_blocks = (N_ + 3) / 4;                 // 4 waves per 256-thread block
    const int alpha_blocks = wave_blocks;
    dim3 gemm_grid(128 / TN, (N_ + TM - 1) / TM);

    // ---- 3 GAT layers ----
    const float* cur_in = x;
    for (int l = 0; l < 3; ++l) {
        k_gemm<<<gemm_grid, 256, 0, stream>>>(cur_in, W[l], nullptr, buf1, N_, 128, 128, 0, 0);
        k_alpha<<<alpha_blocks, 256, 0, stream>>>(buf1, asr[l], ads[l], avs, avd, N_);
        k_aggregate<<<wave_blocks, 256, 0, stream>>>(buf1, off, csrc, avs, avd, bL[l], buf2, N_);
        cur_in = buf2;
    }

    // ---- MLP head ----
    dim3 gm1(256 / TN, (N_ + TM - 1) / TM);
    k_gemm<<<gm1, 256, 0, stream>>>(buf2, Wm1, bm1, buf1, N_, 256, 128, 1, 1);
    k_mlp2<<<wave_blocks, 256, 0, stream>>>(buf1, Wm2, bm2, out, N_);
}

// Round 2
// 714.894 us; speedup vs baseline: 1.1980x; 1.1980x over previous
//
#include <hip/hip_runtime.h>
#include <hip/hip_bf16.h>

// GAT (3 layers) + MLP head. N=50000, E=800000 (+N self loops), D=128, H=256, C=6.
// Round 2: vectorized fp32 GEMM (128x64 tile, 8x4/thread, all-b128 LDS traffic).

#define BM 128
#define BN 64
#define BK 32

__global__ __launch_bounds__(256) void k_hist(const int* __restrict__ ei, int* __restrict__ deg,
                                              int E_, int N_) {
    int e = blockIdx.x * 256 + threadIdx.x;
    int total = E_ + N_;
    if (e >= total) return;
    int d = (e < E_) ? ei[E_ + e] : (e - E_);
    atomicAdd(&deg[d], 1);
}

__global__ __launch_bounds__(1024) void k_scan(const int* __restrict__ deg, int* __restrict__ off, int n) {
    __shared__ int wsum[16];
    __shared__ int wpre[16];
    int tid = threadIdx.x, lane = tid & 63, wid = tid >> 6;
    int carry = 0;
    for (int base = 0; base < n; base += 1024) {
        int i = base + tid;
        int orig = (i < n) ? deg[i] : 0;
        int v = orig;
        #pragma unroll
        for (int d = 1; d < 64; d <<= 1) {
            int t = __shfl_up(v, d);
            if (lane >= d) v += t;
        }
        if (lane == 63) wsum[wid] = v;
        __syncthreads();
        if (wid == 0) {
            int s = (lane < 16) ? wsum[lane] : 0;
            #pragma unroll
            for (int d = 1; d < 16; d <<= 1) {
                int t = __shfl_up(s, d);
                if (lane >= d) s += t;
            }
            if (lane < 16) wpre[lane] = s;
        }
        __syncthreads();
        int woff = (wid > 0) ? wpre[wid - 1] : 0;
        if (i < n) off[i] = carry + woff + (v - orig);
        carry += wpre[15];
        __syncthreads();
    }
    if (tid == 0) off[n] = carry;
}

__global__ __launch_bounds__(256) void k_scatter(const int* __restrict__ ei, const int* __restrict__ off,
                                                 int* __restrict__ cur, int* __restrict__ csrc,
                                                 int E_, int N_) {
    int e = blockIdx.x * 256 + threadIdx.x;
    int total = E_ + N_;
    if (e >= total) return;
    int s, d;
    if (e < E_) { s = ei[e]; d = ei[E_ + e]; }
    else        { s = e - E_; d = e - E_; }
    int pos = off[d] + atomicAdd(&cur[d], 1);
    csrc[pos] = s;
}

// C[M x Ncol] = A[M x K] @ B[K x Ncol] (+bias)(relu).
// 128x64 tile, 256 thr, 8x4 acc/thread, b128 LDS reads, float4 global I/O.
// Requires K % 32 == 0, Ncol % 64 == 0.
__global__ __launch_bounds__(256) void k_gemm(const float* __restrict__ A, const float* __restrict__ B,
                                              const float* __restrict__ bias, float* __restrict__ C,
                                              int M, int Ncol, int K, int has_bias, int relu) {
    __shared__ float As[BK][BM + 4];   // transposed A tile: As[k][m]
    __shared__ float Bs[BK][BN + 4];
    int bm = blockIdx.y * BM;
    int bn = blockIdx.x * BN;
    int tid = threadIdx.x;
    int g = tid >> 4;          // 0..15 row group
    int c = tid & 15;          // 0..15 col group
    int tr0 = g * 4;           // rows tr0..tr0+3 and 64+tr0..64+tr0+3
    int tc = c * 4;
    float acc[8][4] = {};
    for (int k0 = 0; k0 < K; k0 += BK) {
        // stage A: 128 rows x 32 cols, 4 float4 per thread, store transposed
        #pragma unroll
        for (int i = 0; i < 4; ++i) {
            int idx = i * 256 + tid;   // 0..1023
            int row = idx >> 3;        // 0..127
            int j4 = idx & 7;          // 0..7
            int grow = bm + row;
            float4 v = make_float4(0.f, 0.f, 0.f, 0.f);
            if (grow < M) v = *(const float4*)(A + (size_t)grow * K + k0 + j4 * 4);
            As[j4 * 4 + 0][row] = v.x;
            As[j4 * 4 + 1][row] = v.y;
            As[j4 * 4 + 2][row] = v.z;
            As[j4 * 4 + 3][row] = v.w;
        }
        // stage B: 32 rows x 64 cols, 2 float4 per thread, b128 write
        #pragma unroll
        for (int i = 0; i < 2; ++i) {
            int idx = i * 256 + tid;   // 0..511
            int brow = idx >> 4;       // 0..31
            int bc4 = idx & 15;        // 0..15
            float4 v = *(const float4*)(B + (size_t)(k0 + brow) * Ncol + bn + bc4 * 4);
            *(float4*)&Bs[brow][bc4 * 4] = v;
        }
        __syncthreads();
        #pragma unroll
        for (int kk = 0; kk < BK; ++kk) {
            float4 a0 = *(const float4*)&As[kk][tr0];
            float4 a1 = *(const float4*)&As[kk][64 + tr0];
            float4 b  = *(const float4*)&Bs[kk][tc];
            float av[8] = {a0.x, a0.y, a0.z, a0.w, a1.x, a1.y, a1.z, a1.w};
            float bv[4] = {b.x, b.y, b.z, b.w};
            #pragma unroll
            for (int x = 0; x < 8; ++x)
                #pragma unroll
                for (int y = 0; y < 4; ++y)
                    acc[x][y] += av[x] * bv[y];
        }
        __syncthreads();
    }
    #pragma unroll
    for (int x = 0; x < 8; ++x) {
        int row = bm + ((x < 4) ? (tr0 + x) : (64 + tr0 + (x - 4)));
        if (row >= M) continue;
        float4 o;
        float* po = &o.x;
        #pragma unroll
        for (int y = 0; y < 4; ++y) {
            float v = acc[x][y];
            if (has_bias) v += bias[bn + tc + y];
            if (relu) v = fmaxf(v, 0.f);
            po[y] = v;
        }
        *(float4*)(C + (size_t)row * Ncol + bn + tc) = o;
    }
}

// per-node attention coefficients: avs[n] = h[n].asrc, avd[n] = h[n].adst  (D=128)
__global__ __launch_bounds__(256) void k_alpha(const float* __restrict__ h, const float* __restrict__ asrc,
                                               const float* __restrict__ adst, float* __restrict__ avs,
                                               float* __restrict__ avd, int n) {
    int w = (blockIdx.x * 256 + threadIdx.x) >> 6;
    int lane = threadIdx.x & 63;
    if (w >= n) return;
    float h0 = h[(size_t)w * 128 + lane];
    float h1 = h[(size_t)w * 128 + 64 + lane];
    float vs = h0 * asrc[lane] + h1 * asrc[64 + lane];
    float vd = h0 * adst[lane] + h1 * adst[64 + lane];
    #pragma unroll
    for (int d = 32; d > 0; d >>= 1) {
        vs += __shfl_down(vs, d);
        vd += __shfl_down(vd, d);
    }
    if (lane == 0) { avs[w] = vs; avd[w] = vd; }
}

// one wave per dst node: segment softmax (2-pass) + weighted feature aggregate + bias + relu
__global__ __launch_bounds__(256) void k_aggregate(const float* __restrict__ h, const int* __restrict__ off,
                                                   const int* __restrict__ csrc, const float* __restrict__ avs,
                                                   const float* __restrict__ avd, const float* __restrict__ bias,
                                                   float* __restrict__ out, int n) {
    int w = (blockIdx.x * 256 + threadIdx.x) >> 6;
    int lane = threadIdx.x & 63;
    if (w >= n) return;
    int beg = off[w], end = off[w + 1];
    float adn = avd[w];
    // pass 1: max score (edge-parallel across lanes)
    float m = -1e30f;
    for (int j = beg + lane; j < end; j += 64) {
        int s = csrc[j];
        float sc = avs[s] + adn;
        sc = (sc < 0.f) ? 0.2f * sc : sc;
        m = fmaxf(m, sc);
    }
    #pragma unroll
    for (int d = 32; d > 0; d >>= 1) m = fmaxf(m, __shfl_down(m, d));
    m = __shfl(m, 0);
    // pass 2: wave-uniform loop over edges; accumulate e and e*h[src]
    float acc0 = 0.f, acc1 = 0.f, ssum = 0.f;
    for (int j = beg; j < end; ++j) {
        int s = csrc[j];
        float sc = avs[s] + adn;
        sc = (sc < 0.f) ? 0.2f * sc : sc;
        float e = __expf(sc - m);
        ssum += e;
        acc0 += e * h[(size_t)s * 128 + lane];
        acc1 += e * h[(size_t)s * 128 + 64 + lane];
    }
    float inv = 1.f / ssum;
    out[(size_t)w * 128 + lane]      = fmaxf(acc0 * inv + bias[lane], 0.f);
    out[(size_t)w * 128 + 64 + lane] = fmaxf(acc1 * inv + bias[64 + lane], 0.f);
}

// out[n,c] = mid[n,:256] @ Wm2[:,c] + bm2[c]; one wave per node, Wm2 in LDS
__global__ __launch_bounds__(256) void k_mlp2(const float* __restrict__ mid, const float* __restrict__ W2,
                                              const float* __restrict__ b2, float* __restrict__ out, int n) {
    __shared__ float Ws[256 * 6];
    int tid = threadIdx.x;
    for (int t = tid; t < 256 * 6; t += 256) Ws[t] = W2[t];
    __syncthreads();
    int w = (blockIdx.x * 256 + tid) >> 6;
    int lane = tid & 63;
    if (w >= n) return;
    float acc[6] = {0.f, 0.f, 0.f, 0.f, 0.f, 0.f};
    const float* mrow = mid + (size_t)w * 256;
    for (int k = lane; k < 256; k += 64) {
        float mv = mrow[k];
        #pragma unroll
        for (int c = 0; c < 6; ++c) acc[c] += mv * Ws[k * 6 + c];
    }
    #pragma unroll
    for (int c = 0; c < 6; ++c)
        #pragma unroll
        for (int d = 32; d > 0; d >>= 1) acc[c] += __shfl_down(acc[c], d);
    if (lane == 0) {
        #pragma unroll
        for (int c = 0; c < 6; ++c) out[(size_t)w * 6 + c] = acc[c] + b2[c];
    }
}

extern "C" void kernel_launch(void* const* d_in, const int* in_sizes, int n_in,
                              void* d_out, int out_size, void* d_ws, size_t ws_size,
                              hipStream_t stream) {
    const float* x   = (const float*)d_in[0];
    const int*   ei  = (const int*)d_in[1];
    const float* W[3]    = {(const float*)d_in[2], (const float*)d_in[6], (const float*)d_in[10]};
    const float* bL[3]   = {(const float*)d_in[3], (const float*)d_in[7], (const float*)d_in[11]};
    const float* asr[3]  = {(const float*)d_in[4], (const float*)d_in[8], (const float*)d_in[12]};
    const float* ads[3]  = {(const float*)d_in[5], (const float*)d_in[9], (const float*)d_in[13]};
    const float* Wm1 = (const float*)d_in[14];
    const float* bm1 = (const float*)d_in[15];
    const float* Wm2 = (const float*)d_in[16];
    const float* bm2 = (const float*)d_in[17];
    float* out = (float*)d_out;

    const int N_ = in_sizes[0] / 128;
    const int E_ = in_sizes[1] / 2;
    const int TOT = E_ + N_;

    // workspace carve-up (256B aligned)
    char* p = (char*)d_ws;
    auto alloc = [&](size_t bytes) { void* r = (void*)p; p += (bytes + 255) & ~(size_t)255; return r; };
    int*   deg  = (int*)alloc((size_t)N_ * 4);
    int*   cur  = (int*)alloc((size_t)N_ * 4);
    int*   off  = (int*)alloc((size_t)(N_ + 1) * 4);
    int*   csrc = (int*)alloc((size_t)TOT * 4);
    float* avs  = (float*)alloc((size_t)N_ * 4);
    float* avd  = (float*)alloc((size_t)N_ * 4);
    float* buf1 = (float*)alloc((size_t)N_ * 256 * 4);  // h-transform (128 cols) / mlp mid (256 cols)
    float* buf2 = (float*)alloc((size_t)N_ * 128 * 4);  // aggregated layer output

    // ---- CSR build ----
    hipMemsetAsync(deg, 0, (size_t)N_ * 4, stream);
    k_hist<<<(TOT + 255) / 256, 256, 0, stream>>>(ei, deg, E_, N_);
    k_scan<<<1, 1024, 0, stream>>>(deg, off, N_);
    hipMemsetAsync(cur, 0, (size_t)N_ * 4, stream);
    k_scatter<<<(TOT + 255) / 256, 256, 0, stream>>>(ei, off, cur, csrc, E_, N_);

    const int wave_blocks = (N_ + 3) / 4;                 // 4 waves per 256-thread block
    dim3 gemm_grid(128 / BN, (N_ + BM - 1) / BM);

    // ---- 3 GAT layers ----
    const float* cur_in = x;
    for (int l = 0; l < 3; ++l) {
        k_gemm<<<gemm_grid, 256, 0, stream>>>(cur_in, W[l], nullptr, buf1, N_, 128, 128, 0, 0);
        k_alpha<<<wave_blocks, 256, 0, stream>>>(buf1, asr[l], ads[l], avs, avd, N_);
        k_aggregate<<<wave_blocks, 256, 0, stream>>>(buf1, off, csrc, avs, avd, bL[l], buf2, N_);
        cur_in = buf2;
    }

    // ---- MLP head ----
    dim3 gm1(256 / BN, (N_ + BM - 1) / BM);
    k_gemm<<<gm1, 256, 0, stream>>>(buf2, Wm1, bm1, buf1, N_, 256, 128, 1, 1);
    k_mlp2<<<wave_blocks, 256, 0, stream>>>(buf1, Wm2, bm2, out, N_);
}

// Round 3
// 602.886 us; speedup vs baseline: 1.4206x; 1.1858x over previous
//
#include <hip/hip_runtime.h>
#include <hip/hip_bf16.h>

// GAT (3 layers) + MLP head. N=50000, E=800000 (+N self loops), D=128, H=256, C=6.
// Round 3: aggregate gather restructured — half-wave per edge, float4 row loads,
// 2x unroll (4 edges in flight per wave). GEMM unchanged from round 2.

#define BM 128
#define BN 64
#define BK 32

__global__ __launch_bounds__(256) void k_hist(const int* __restrict__ ei, int* __restrict__ deg,
                                              int E_, int N_) {
    int e = blockIdx.x * 256 + threadIdx.x;
    int total = E_ + N_;
    if (e >= total) return;
    int d = (e < E_) ? ei[E_ + e] : (e - E_);
    atomicAdd(&deg[d], 1);
}

__global__ __launch_bounds__(1024) void k_scan(const int* __restrict__ deg, int* __restrict__ off, int n) {
    __shared__ int wsum[16];
    __shared__ int wpre[16];
    int tid = threadIdx.x, lane = tid & 63, wid = tid >> 6;
    int carry = 0;
    for (int base = 0; base < n; base += 1024) {
        int i = base + tid;
        int orig = (i < n) ? deg[i] : 0;
        int v = orig;
        #pragma unroll
        for (int d = 1; d < 64; d <<= 1) {
            int t = __shfl_up(v, d);
            if (lane >= d) v += t;
        }
        if (lane == 63) wsum[wid] = v;
        __syncthreads();
        if (wid == 0) {
            int s = (lane < 16) ? wsum[lane] : 0;
            #pragma unroll
            for (int d = 1; d < 16; d <<= 1) {
                int t = __shfl_up(s, d);
                if (lane >= d) s += t;
            }
            if (lane < 16) wpre[lane] = s;
        }
        __syncthreads();
        int woff = (wid > 0) ? wpre[wid - 1] : 0;
        if (i < n) off[i] = carry + woff + (v - orig);
        carry += wpre[15];
        __syncthreads();
    }
    if (tid == 0) off[n] = carry;
}

__global__ __launch_bounds__(256) void k_scatter(const int* __restrict__ ei, const int* __restrict__ off,
                                                 int* __restrict__ cur, int* __restrict__ csrc,
                                                 int E_, int N_) {
    int e = blockIdx.x * 256 + threadIdx.x;
    int total = E_ + N_;
    if (e >= total) return;
    int s, d;
    if (e < E_) { s = ei[e]; d = ei[E_ + e]; }
    else        { s = e - E_; d = e - E_; }
    int pos = off[d] + atomicAdd(&cur[d], 1);
    csrc[pos] = s;
}

// C[M x Ncol] = A[M x K] @ B[K x Ncol] (+bias)(relu).
// 128x64 tile, 256 thr, 8x4 acc/thread, b128 LDS reads, float4 global I/O.
__global__ __launch_bounds__(256) void k_gemm(const float* __restrict__ A, const float* __restrict__ B,
                                              const float* __restrict__ bias, float* __restrict__ C,
                                              int M, int Ncol, int K, int has_bias, int relu) {
    __shared__ float As[BK][BM + 4];   // transposed A tile: As[k][m]
    __shared__ float Bs[BK][BN + 4];
    int bm = blockIdx.y * BM;
    int bn = blockIdx.x * BN;
    int tid = threadIdx.x;
    int g = tid >> 4;          // 0..15 row group
    int c = tid & 15;          // 0..15 col group
    int tr0 = g * 4;
    int tc = c * 4;
    float acc[8][4] = {};
    for (int k0 = 0; k0 < K; k0 += BK) {
        #pragma unroll
        for (int i = 0; i < 4; ++i) {
            int idx = i * 256 + tid;
            int row = idx >> 3;
            int j4 = idx & 7;
            int grow = bm + row;
            float4 v = make_float4(0.f, 0.f, 0.f, 0.f);
            if (grow < M) v = *(const float4*)(A + (size_t)grow * K + k0 + j4 * 4);
            As[j4 * 4 + 0][row] = v.x;
            As[j4 * 4 + 1][row] = v.y;
            As[j4 * 4 + 2][row] = v.z;
            As[j4 * 4 + 3][row] = v.w;
        }
        #pragma unroll
        for (int i = 0; i < 2; ++i) {
            int idx = i * 256 + tid;
            int brow = idx >> 4;
            int bc4 = idx & 15;
            float4 v = *(const float4*)(B + (size_t)(k0 + brow) * Ncol + bn + bc4 * 4);
            *(float4*)&Bs[brow][bc4 * 4] = v;
        }
        __syncthreads();
        #pragma unroll
        for (int kk = 0; kk < BK; ++kk) {
            float4 a0 = *(const float4*)&As[kk][tr0];
            float4 a1 = *(const float4*)&As[kk][64 + tr0];
            float4 b  = *(const float4*)&Bs[kk][tc];
            float av[8] = {a0.x, a0.y, a0.z, a0.w, a1.x, a1.y, a1.z, a1.w};
            float bv[4] = {b.x, b.y, b.z, b.w};
            #pragma unroll
            for (int x = 0; x < 8; ++x)
                #pragma unroll
                for (int y = 0; y < 4; ++y)
                    acc[x][y] += av[x] * bv[y];
        }
        __syncthreads();
    }
    #pragma unroll
    for (int x = 0; x < 8; ++x) {
        int row = bm + ((x < 4) ? (tr0 + x) : (64 + tr0 + (x - 4)));
        if (row >= M) continue;
        float4 o;
        float* po = &o.x;
        #pragma unroll
        for (int y = 0; y < 4; ++y) {
            float v = acc[x][y];
            if (has_bias) v += bias[bn + tc + y];
            if (relu) v = fmaxf(v, 0.f);
            po[y] = v;
        }
        *(float4*)(C + (size_t)row * Ncol + bn + tc) = o;
    }
}

// per-node attention coefficients: avs[n] = h[n].asrc, avd[n] = h[n].adst  (D=128)
__global__ __launch_bounds__(256) void k_alpha(const float* __restrict__ h, const float* __restrict__ asrc,
                                               const float* __restrict__ adst, float* __restrict__ avs,
                                               float* __restrict__ avd, int n) {
    int w = (blockIdx.x * 256 + threadIdx.x) >> 6;
    int lane = threadIdx.x & 63;
    if (w >= n) return;
    float2 hv = ((const float2*)(h + (size_t)w * 128))[lane];
    float2 s2 = ((const float2*)asrc)[lane];
    float2 d2 = ((const float2*)adst)[lane];
    float vs = hv.x * s2.x + hv.y * s2.y;
    float vd = hv.x * d2.x + hv.y * d2.y;
    #pragma unroll
    for (int d = 32; d > 0; d >>= 1) {
        vs += __shfl_down(vs, d);
        vd += __shfl_down(vd, d);
    }
    if (lane == 0) { avs[w] = vs; avd[w] = vd; }
}

// one wave per dst node: 2-pass segment softmax + weighted aggregate + bias + relu.
// Pass 2: half-wave (32 lanes) per edge, float4 row loads, 2x unroll (4 edges in flight).
__global__ __launch_bounds__(256) void k_aggregate(const float* __restrict__ h, const int* __restrict__ off,
                                                   const int* __restrict__ csrc, const float* __restrict__ avs,
                                                   const float* __restrict__ avd, const float* __restrict__ bias,
                                                   float* __restrict__ out, int n) {
    int w = (blockIdx.x * 256 + threadIdx.x) >> 6;
    int lane = threadIdx.x & 63;
    if (w >= n) return;
    int half = lane >> 5;      // 0/1: which edge parity this half-wave owns
    int sl = lane & 31;        // feature quad index within the row
    int beg = off[w], end = off[w + 1];
    float adn = avd[w];
    // pass 1: max score, edge-parallel across all 64 lanes
    float m = -1e30f;
    for (int j = beg + lane; j < end; j += 64) {
        float sc = avs[csrc[j]] + adn;
        sc = (sc < 0.f) ? 0.2f * sc : sc;
        m = fmaxf(m, sc);
    }
    #pragma unroll
    for (int d = 32; d > 0; d >>= 1) m = fmaxf(m, __shfl_xor(m, d));
    // pass 2: half-wave per edge, stride 2 per half; 2x unroll
    float4 acc = make_float4(0.f, 0.f, 0.f, 0.f);
    float ssum = 0.f;
    int j = beg + half;
    for (; j + 2 < end; j += 4) {
        int s0 = csrc[j];
        int s1 = csrc[j + 2];
        float4 h0 = *((const float4*)(h + (size_t)s0 * 128) + sl);
        float4 h1 = *((const float4*)(h + (size_t)s1 * 128) + sl);
        float sc0 = avs[s0] + adn; sc0 = (sc0 < 0.f) ? 0.2f * sc0 : sc0;
        float sc1 = avs[s1] + adn; sc1 = (sc1 < 0.f) ? 0.2f * sc1 : sc1;
        float e0 = __expf(sc0 - m);
        float e1 = __expf(sc1 - m);
        ssum += e0 + e1;
        acc.x += e0 * h0.x + e1 * h1.x;
        acc.y += e0 * h0.y + e1 * h1.y;
        acc.z += e0 * h0.z + e1 * h1.z;
        acc.w += e0 * h0.w + e1 * h1.w;
    }
    for (; j < end; j += 2) {
        int s0 = csrc[j];
        float4 h0 = *((const float4*)(h + (size_t)s0 * 128) + sl);
        float sc0 = avs[s0] + adn; sc0 = (sc0 < 0.f) ? 0.2f * sc0 : sc0;
        float e0 = __expf(sc0 - m);
        ssum += e0;
        acc.x += e0 * h0.x;
        acc.y += e0 * h0.y;
        acc.z += e0 * h0.z;
        acc.w += e0 * h0.w;
    }
    // combine the two halves (each lane pairs with lane^32, same feature quad)
    ssum  += __shfl_xor(ssum, 32);
    acc.x += __shfl_xor(acc.x, 32);
    acc.y += __shfl_xor(acc.y, 32);
    acc.z += __shfl_xor(acc.z, 32);
    acc.w += __shfl_xor(acc.w, 32);
    if (half == 0) {
        float inv = 1.f / ssum;
        float4 b = ((const float4*)bias)[sl];
        float4 o;
        o.x = fmaxf(acc.x * inv + b.x, 0.f);
        o.y = fmaxf(acc.y * inv + b.y, 0.f);
        o.z = fmaxf(acc.z * inv + b.z, 0.f);
        o.w = fmaxf(acc.w * inv + b.w, 0.f);
        *((float4*)(out + (size_t)w * 128) + sl) = o;
    }
}

// out[n,c] = mid[n,:256] @ Wm2[:,c] + bm2[c]; one wave per node, Wm2 in LDS
__global__ __launch_bounds__(256) void k_mlp2(const float* __restrict__ mid, const float* __restrict__ W2,
                                              const float* __restrict__ b2, float* __restrict__ out, int n) {
    __shared__ float Ws[256 * 6];
    int tid = threadIdx.x;
    for (int t = tid; t < 256 * 6; t += 256) Ws[t] = W2[t];
    __syncthreads();
    int w = (blockIdx.x * 256 + tid) >> 6;
    int lane = tid & 63;
    if (w >= n) return;
    float acc[6] = {0.f, 0.f, 0.f, 0.f, 0.f, 0.f};
    float4 mv = ((const float4*)(mid + (size_t)w * 256))[lane];
    int k0 = lane * 4;
    #pragma unroll
    for (int c = 0; c < 6; ++c)
        acc[c] = mv.x * Ws[k0 * 6 + c] + mv.y * Ws[(k0 + 1) * 6 + c]
               + mv.z * Ws[(k0 + 2) * 6 + c] + mv.w * Ws[(k0 + 3) * 6 + c];
    #pragma unroll
    for (int c = 0; c < 6; ++c)
        #pragma unroll
        for (int d = 32; d > 0; d >>= 1) acc[c] += __shfl_down(acc[c], d);
    if (lane == 0) {
        #pragma unroll
        for (int c = 0; c < 6; ++c) out[(size_t)w * 6 + c] = acc[c] + b2[c];
    }
}

extern "C" void kernel_launch(void* const* d_in, const int* in_sizes, int n_in,
                              void* d_out, int out_size, void* d_ws, size_t ws_size,
                              hipStream_t stream) {
    const float* x   = (const float*)d_in[0];
    const int*   ei  = (const int*)d_in[1];
    const float* W[3]    = {(const float*)d_in[2], (const float*)d_in[6], (const float*)d_in[10]};
    const float* bL[3]   = {(const float*)d_in[3], (const float*)d_in[7], (const float*)d_in[11]};
    const float* asr[3]  = {(const float*)d_in[4], (const float*)d_in[8], (const float*)d_in[12]};
    const float* ads[3]  = {(const float*)d_in[5], (const float*)d_in[9], (const float*)d_in[13]};
    const float* Wm1 = (const float*)d_in[14];
    const float* bm1 = (const float*)d_in[15];
    const float* Wm2 = (const float*)d_in[16];
    const float* bm2 = (const float*)d_in[17];
    float* out = (float*)d_out;

    const int N_ = in_sizes[0] / 128;
    const int E_ = in_sizes[1] / 2;
    const int TOT = E_ + N_;

    char* p = (char*)d_ws;
    auto alloc = [&](size_t bytes) { void* r = (void*)p; p += (bytes + 255) & ~(size_t)255; return r; };
    int*   deg  = (int*)alloc((size_t)N_ * 4);
    int*   cur  = (int*)alloc((size_t)N_ * 4);
    int*   off  = (int*)alloc((size_t)(N_ + 1) * 4);
    int*   csrc = (int*)alloc((size_t)TOT * 4);
    float* avs  = (float*)alloc((size_t)N_ * 4);
    float* avd  = (float*)alloc((size_t)N_ * 4);
    float* buf1 = (float*)alloc((size_t)N_ * 256 * 4);
    float* buf2 = (float*)alloc((size_t)N_ * 128 * 4);

    // ---- CSR build ----
    hipMemsetAsync(deg, 0, (size_t)N_ * 4, stream);
    k_hist<<<(TOT + 255) / 256, 256, 0, stream>>>(ei, deg, E_, N_);
    k_scan<<<1, 1024, 0, stream>>>(deg, off, N_);
    hipMemsetAsync(cur, 0, (size_t)N_ * 4, stream);
    k_scatter<<<(TOT + 255) / 256, 256, 0, stream>>>(ei, off, cur, csrc, E_, N_);

    const int wave_blocks = (N_ + 3) / 4;
    dim3 gemm_grid(128 / BN, (N_ + BM - 1) / BM);

    // ---- 3 GAT layers ----
    const float* cur_in = x;
    for (int l = 0; l < 3; ++l) {
        k_gemm<<<gemm_grid, 256, 0, stream>>>(cur_in, W[l], nullptr, buf1, N_, 128, 128, 0, 0);
        k_alpha<<<wave_blocks, 256, 0, stream>>>(buf1, asr[l], ads[l], avs, avd, N_);
        k_aggregate<<<wave_blocks, 256, 0, stream>>>(buf1, off, csrc, avs, avd, bL[l], buf2, N_);
        cur_in = buf2;
    }

    // ---- MLP head ----
    dim3 gm1(256 / BN, (N_ + BM - 1) / BM);
    k_gemm<<<gm1, 256, 0, stream>>>(buf2, Wm1, bm1, buf1, N_, 256, 128, 1, 1);
    k_mlp2<<<wave_blocks, 256, 0, stream>>>(buf1, Wm2, bm2, out, N_);
}